// Round 9
// baseline (264.159 us; speedup 1.0000x reference)
//
#include <hip/hip_runtime.h>
#include <hip/hip_bf16.h>

typedef __attribute__((ext_vector_type(8))) short short8;
typedef __attribute__((ext_vector_type(4))) float floatx4;

#define NIN 2056
#define KPAD 2080
#define NBS 4096

// ---------------- async global->LDS (16B) ----------------
__device__ __forceinline__ void gl_lds16(const ushort* g, ushort* l) {
#if defined(__has_builtin) && __has_builtin(__builtin_amdgcn_global_load_lds)
  __builtin_amdgcn_global_load_lds(
      (const __attribute__((address_space(1))) unsigned int*)g,
      (__attribute__((address_space(3))) unsigned int*)l, 16, 0, 0);
#else
  *(uint4*)l = *(const uint4*)g;
#endif
}

// ---------------- reductions ----------------
__device__ __forceinline__ float wsum(float v) {
#pragma unroll
  for (int o = 32; o; o >>= 1) v += __shfl_xor(v, o, 64);
  return v;
}
__device__ __forceinline__ float wmax(float v) {
#pragma unroll
  for (int o = 32; o; o >>= 1) v = fmaxf(v, __shfl_xor(v, o, 64));
  return v;
}

// ---------------- merged small preps ----------------
// [0,512): mmat; [512,704): w1cat; [704,896): w1m+b1cat; [896,1280): w2cat;
// 1280: wkeT; 1281: wkaT
__global__ void prep_small(const float* __restrict__ obs,
                           const float* __restrict__ Wb1, const float* __restrict__ Wh1,
                           const float* __restrict__ Wq1, const float* __restrict__ Wkm1,
                           const float* __restrict__ Wvm1, const float* __restrict__ bq1,
                           const float* __restrict__ bkm1, const float* __restrict__ bvm1,
                           const float* __restrict__ Wq2, const float* __restrict__ Wkm2,
                           const float* __restrict__ Wvm2,
                           const float* __restrict__ Wke, const float* __restrict__ Wka,
                           __hip_bfloat16* __restrict__ mmat,
                           __hip_bfloat16* __restrict__ w1cat,
                           __hip_bfloat16* __restrict__ w1m, float* __restrict__ b1cat,
                           __hip_bfloat16* __restrict__ w2cat,
                           __hip_bfloat16* __restrict__ wket,
                           __hip_bfloat16* __restrict__ wkat) {
  int bid = blockIdx.x, tid = threadIdx.x;
  if (bid < 512) {  // mmat [4096][32]
    int idx = bid * 256 + tid;
    int b = idx >> 5, j = idx & 31;
    float v = 0.f;
    if (j < 4) v = obs[(size_t)b * NIN + j];
    else if (j < 24) v = obs[(size_t)b * NIN + 2032 + j];
    mmat[idx] = __float2bfloat16(v);
  } else if (bid < 704) {  // w1cat [192][KPAD]
    int r = bid - 512;
    const float* src = (r < 64) ? (Wb1 + (size_t)r * NIN) : (Wh1 + (size_t)(r - 64) * NIN);
    for (int j = tid; j < KPAD; j += 256)
      w1cat[(size_t)r * KPAD + j] = __float2bfloat16(j < NIN ? src[j] : 0.f);
  } else if (bid < 896) {  // w1m [1536][32], b1cat
    int idx = (bid - 704) * 256 + tid;
    int row = idx >> 5, j = idx & 31;
    int net = row >> 9, hg = row & 511;
    const float* W1 = net == 0 ? Wq1 : (net == 1 ? Wkm1 : Wvm1);
    float v = (j < 24) ? W1[(size_t)hg * 24 + j] : 0.f;
    w1m[idx] = __float2bfloat16(v);
    if (j == 0) {
      const float* b1 = net == 0 ? bq1 : (net == 1 ? bkm1 : bvm1);
      b1cat[row] = b1[hg];
    }
  } else if (bid < 1280) {  // w2cat [768][128]
    int idx = (bid - 896) * 256 + tid;
    int row = idx >> 7, g = idx & 127;
    int net = row >> 8, he = row & 255;
    const float* W2 = net == 0 ? Wq2 : (net == 1 ? Wkm2 : Wvm2);
    w2cat[idx] = __float2bfloat16(W2[(size_t)he * 128 + g]);
  } else {  // wkeT/wkaT [h*16+d][64 e] bf16
    const float* W = (bid == 1280) ? Wke : Wka;
    __hip_bfloat16* dst = (bid == 1280) ? wket : wkat;
    for (int j = tid; j < 4096; j += 256) {
      int e = j & 63, hd = j >> 6;
      int h = hd >> 4, d = hd & 15;
      dst[j] = __float2bfloat16(W[h * 1024 + e * 16 + d]);
    }
  }
}

// transpose Wf [256][8192] -> Wft [8192][256]; fold in rowsum
__global__ void p6a_twf(const float* __restrict__ Wf, float* __restrict__ Wft,
                        float* __restrict__ rowsum) {
  __shared__ float t[64][65];
  int kt = blockIdx.x, rt = blockIdx.y;
  int tid = threadIdx.x;
  int kl = tid & 63, r0 = tid >> 6;
#pragma unroll
  for (int ii = 0; ii < 16; ++ii) {
    int rl = ii * 4 + r0;
    t[rl][kl] = Wf[(size_t)(rt * 64 + rl) * 8192 + kt * 64 + kl];
  }
  __syncthreads();
#pragma unroll
  for (int ii = 0; ii < 16; ++ii) {
    int kl2 = ii * 4 + r0;
    Wft[(size_t)(kt * 64 + kl2) * 256 + rt * 64 + kl] = t[kl][kl2];
  }
  if (tid < 64) {
    float s = 0.f;
    for (int kk = 0; kk < 64; ++kk) s += t[tid][kk];
    atomicAdd(&rowsum[rt * 64 + tid], s);
  }
}

// Yt layout: k = h*2048 + (n-1)*16 + d for entities; e-basis at h'*2048+2032+(e&15)
__global__ void p6b_yt(const float* __restrict__ Wft, const float* __restrict__ Wve,
                       const float* __restrict__ Wva, __hip_bfloat16* __restrict__ Yt) {
  int n = blockIdx.x;   // 0..127
  int r = threadIdx.x;  // 0..255
  if (n == 0) {
    alignas(16) __hip_bfloat16 tmp[8];
    for (int e0 = 0; e0 < 64; e0 += 8) {
#pragma unroll
      for (int j = 0; j < 8; ++j)
        tmp[j] = __float2bfloat16(Wft[(size_t)((e0 + j) * 128) * 256 + r]);
      *(uint4*)(Yt + (size_t)r * 8192 + (e0 >> 4) * 2048 + 2032 + (e0 & 15)) =
          *(const uint4*)tmp;
    }
    return;
  }
  const float* Wv = (n <= 64) ? Wve : Wva;
  float accv[64];
#pragma unroll
  for (int j = 0; j < 64; ++j) accv[j] = 0.f;
  for (int e = 0; e < 64; ++e) {
    float v = Wft[(size_t)(e * 128 + n) * 256 + r];
#pragma unroll
    for (int hd = 0; hd < 64; ++hd)
      accv[hd] += Wv[(hd >> 4) * 1024 + e * 16 + (hd & 15)] * v;
  }
#pragma unroll
  for (int c = 0; c < 8; ++c) {
    alignas(16) __hip_bfloat16 tmp[8];
#pragma unroll
    for (int j = 0; j < 8; ++j) tmp[j] = __float2bfloat16(accv[c * 8 + j]);
    // hd = c*8+j -> h = c>>1, d = (c&1)*8+j
    *(uint4*)(Yt + (size_t)r * 8192 + (c >> 1) * 2048 + (size_t)(n - 1) * 16 + (c & 1) * 8) =
        *(const uint4*)tmp;
  }
}

// ---------------- fused HID+QKV (+ qke/qka MFMA for z<4) ----------------
__global__ __launch_bounds__(256) void qkv_fused(
    const __hip_bfloat16* __restrict__ mmat_, const __hip_bfloat16* __restrict__ w1m_,
    const float* __restrict__ b1cat, const __hip_bfloat16* __restrict__ w2cat_,
    const __hip_bfloat16* __restrict__ wket_, const __hip_bfloat16* __restrict__ wkat_,
    float* __restrict__ QKV, float* __restrict__ QKE, float* __restrict__ QKA) {
  __shared__ alignas(16) ushort lH[64 * 136];
  __shared__ alignas(16) ushort lq[64 * 72];
  const ushort* mmat = (const ushort*)mmat_;
  const ushort* w1m = (const ushort*)w1m_;
  const ushort* w2cat = (const ushort*)w2cat_;
  const ushort* wket = (const ushort*)wket_;
  const ushort* wkat = (const ushort*)wkat_;
  int mt = blockIdx.x, z = blockIdx.y;
  int t = threadIdx.x;
  int w = t >> 6, l = t & 63, r16 = l & 15, kg = l >> 4;
  floatx4 zero4 = {0.f, 0.f, 0.f, 0.f};
  // GEMM1: hidden = relu(mmat * w1m[z]^T + b1)
  short8 a1 = *(const short8*)(mmat + (size_t)(mt * 64 + w * 16 + r16) * 32 + kg * 8);
  floatx4 acc1[8];
#pragma unroll
  for (int c = 0; c < 8; ++c) {
    short8 b1 = *(const short8*)(w1m + (size_t)(z * 128 + c * 16 + r16) * 32 + kg * 8);
    acc1[c] = __builtin_amdgcn_mfma_f32_16x16x32_bf16(a1, b1, zero4, 0, 0, 0);
  }
#pragma unroll
  for (int c = 0; c < 8; ++c) {
    int col = c * 16 + r16;
    float bias = b1cat[z * 128 + col];
#pragma unroll
    for (int r = 0; r < 4; ++r) {
      float v = acc1[c][r] + bias;
      v = v > 0.f ? v : 0.f;
      __hip_bfloat16 bv = __float2bfloat16(v);
      lH[(w * 16 + kg * 4 + r) * 136 + col] = *(ushort*)&bv;
    }
  }
  __syncthreads();
  // GEMM2: out = hidden * w2cat[z]^T
  floatx4 acc2[4] = {zero4, zero4, zero4, zero4};
#pragma unroll
  for (int ks = 0; ks < 4; ++ks) {
    short8 a = *(const short8*)(lH + (w * 16 + r16) * 136 + ks * 32 + kg * 8);
#pragma unroll
    for (int c = 0; c < 4; ++c) {
      short8 b = *(const short8*)(w2cat + (size_t)(z * 64 + c * 16 + r16) * 128 + ks * 32 + kg * 8);
      acc2[c] = __builtin_amdgcn_mfma_f32_16x16x32_bf16(a, b, acc2[c], 0, 0, 0);
    }
  }
  float* Q = QKV + (size_t)(mt * 64) * 768 + z * 64;
#pragma unroll
  for (int c = 0; c < 4; ++c)
#pragma unroll
    for (int r = 0; r < 4; ++r)
      Q[(size_t)(w * 16 + kg * 4 + r) * 768 + c * 16 + r16] = acc2[c][r];
  // qke/qka = q @ WkeT/WkaT via MFMA (q heads only: z<4, h=z)
  if (z < 4) {
#pragma unroll
    for (int c = 0; c < 4; ++c)
#pragma unroll
      for (int r = 0; r < 4; ++r) {
        __hip_bfloat16 bv = __float2bfloat16(acc2[c][r]);
        lq[(w * 16 + kg * 4 + r) * 72 + c * 16 + r16] = *(ushort*)&bv;
      }
    short8 a0 = *(const short8*)(lq + (w * 16 + r16) * 72 + kg * 8);
    short8 a1q = *(const short8*)(lq + (w * 16 + r16) * 72 + 32 + kg * 8);
    const ushort* bke = wket + (size_t)(z * 16 + r16) * 64 + kg * 8;
    const ushort* bka = wkat + (size_t)(z * 16 + r16) * 64 + kg * 8;
    short8 bk0 = *(const short8*)bke;
    short8 bk1 = *(const short8*)(bke + 32);
    short8 ba0 = *(const short8*)bka;
    short8 ba1 = *(const short8*)(bka + 32);
    floatx4 ke = __builtin_amdgcn_mfma_f32_16x16x32_bf16(a0, bk0, zero4, 0, 0, 0);
    ke = __builtin_amdgcn_mfma_f32_16x16x32_bf16(a1q, bk1, ke, 0, 0, 0);
    floatx4 ka = __builtin_amdgcn_mfma_f32_16x16x32_bf16(a0, ba0, zero4, 0, 0, 0);
    ka = __builtin_amdgcn_mfma_f32_16x16x32_bf16(a1q, ba1, ka, 0, 0, 0);
#pragma unroll
    for (int r = 0; r < 4; ++r) {
      size_t row = (size_t)(mt * 64 + w * 16 + kg * 4 + r);
      QKE[row * 64 + z * 16 + r16] = ke[r];
      QKA[row * 64 + z * 16 + r16] = ka[r];
    }
  }
}

// ---------------- H1 GEMM: 64 rows x 192 cols per block, split-K=8 ----------------
// z chunk covers K-iters [z*8, z*8+8); z==7 also takes the padded tail iter 64.
__global__ __launch_bounds__(256) void gemm_h1(
    const float* __restrict__ obs, const __hip_bfloat16* __restrict__ w1cat_,
    float* __restrict__ H1p) {
  __shared__ alignas(16) ushort lA[64 * 40];
  __shared__ alignas(16) ushort lB[192 * 40];
  const ushort* w1cat = (const ushort*)w1cat_;
  int mt = blockIdx.x, z = blockIdx.y;
  int t = threadIdx.x;
  int w = t >> 6, l = t & 63, r16 = l & 15, kg = l >> 4;
  int srow = t >> 2, sc = (t & 3) * 8;
  int k0 = z * 256;
  const float* ga = obs + (size_t)(mt * 64 + srow) * NIN + k0 + sc;
  ushort* sa = lA + srow * 40 + sc;
  const ushort* fa = lA + (w * 16 + r16) * 40 + kg * 8;
  floatx4 zero4 = {0.f, 0.f, 0.f, 0.f};
  floatx4 acc[12];
#pragma unroll
  for (int c = 0; c < 12; ++c) acc[c] = zero4;
  int nK = (z == 7) ? 9 : 8;
  for (int ks = 0; ks < nK; ++ks) {
    float4 f0, f1;
    bool tail = (z == 7 && ks == 8);  // global K-iter 64: only k=2048..2055 valid
    if (!tail || (t & 3) == 0) {
      f0 = *(const float4*)(ga + ks * 32);
      f1 = *(const float4*)(ga + ks * 32 + 4);
    } else {
      f0 = make_float4(0.f, 0.f, 0.f, 0.f);
      f1 = make_float4(0.f, 0.f, 0.f, 0.f);
    }
    uint4 vb[3];
#pragma unroll
    for (int i = 0; i < 3; ++i)
      vb[i] = *(const uint4*)(w1cat + (size_t)(i * 64 + srow) * KPAD + k0 + sc + ks * 32);
    __syncthreads();
    alignas(16) __hip_bfloat16 tmp[8];
    tmp[0] = __float2bfloat16(f0.x); tmp[1] = __float2bfloat16(f0.y);
    tmp[2] = __float2bfloat16(f0.z); tmp[3] = __float2bfloat16(f0.w);
    tmp[4] = __float2bfloat16(f1.x); tmp[5] = __float2bfloat16(f1.y);
    tmp[6] = __float2bfloat16(f1.z); tmp[7] = __float2bfloat16(f1.w);
    *(uint4*)sa = *(const uint4*)tmp;
#pragma unroll
    for (int i = 0; i < 3; ++i)
      *(uint4*)(lB + (i * 64 + srow) * 40 + sc) = vb[i];
    __syncthreads();
    short8 a = *(const short8*)fa;
#pragma unroll
    for (int c = 0; c < 12; ++c) {
      short8 bb = *(const short8*)(lB + (c * 16 + r16) * 40 + kg * 8);
      acc[c] = __builtin_amdgcn_mfma_f32_16x16x32_bf16(a, bb, acc[c], 0, 0, 0);
    }
  }
  float* C = H1p + (size_t)z * NBS * 192;
  int row0 = mt * 64 + w * 16 + kg * 4;
#pragma unroll
  for (int c = 0; c < 12; ++c)
#pragma unroll
    for (int r = 0; r < 4; ++r)
      C[(size_t)(row0 + r) * 192 + c * 16 + r16] = acc[c][r];
}

// ---------------- final GEMM: 128x128 tile, BK=32, split-K=8 ----------------
__global__ __launch_bounds__(256) void gemm_final(
    const ushort* __restrict__ Xg, const ushort* __restrict__ Yt,
    float* __restrict__ part) {
  __shared__ alignas(16) ushort lA[128 * 32];
  __shared__ alignas(16) ushort lB[128 * 32];
  int bid = blockIdx.x;
  int z = bid & 7, nt = (bid >> 3) & 1, mt = bid >> 4;
  int t = threadIdx.x;
  int w = t >> 6, l = t & 63, r16 = l & 15, kg = l >> 4;
  int wr = (w >> 1) * 64, wc = (w & 1) * 64;
  const ushort* ga0 = Xg + (size_t)(mt * 128 + (t >> 2)) * 8192 + z * 1024 + (t & 3) * 8;
  const ushort* ga1 = ga0 + (size_t)64 * 8192;
  const ushort* gb0 = Yt + (size_t)(nt * 128 + (t >> 2)) * 8192 + z * 1024 + (t & 3) * 8;
  const ushort* gb1 = gb0 + (size_t)64 * 8192;
  ushort* la0 = lA + t * 8;
  ushort* la1 = lA + 2048 + t * 8;
  ushort* lb0 = lB + t * 8;
  ushort* lb1 = lB + 2048 + t * 8;
  const ushort* fa0 = lA + (wr + r16) * 32 + kg * 8;
  const ushort* fb0 = lB + (wc + r16) * 32 + kg * 8;
  floatx4 zero4 = {0.f, 0.f, 0.f, 0.f};
  floatx4 acc[4][4];
#pragma unroll
  for (int i = 0; i < 4; ++i)
#pragma unroll
    for (int j = 0; j < 4; ++j) acc[i][j] = zero4;
  for (int ks = 0; ks < 32; ++ks) {
    gl_lds16(ga0, la0);
    gl_lds16(ga1, la1);
    gl_lds16(gb0, lb0);
    gl_lds16(gb1, lb1);
    ga0 += 32; ga1 += 32; gb0 += 32; gb1 += 32;
    __syncthreads();
    short8 a[4], b[4];
#pragma unroll
    for (int mi = 0; mi < 4; ++mi) a[mi] = *(const short8*)(fa0 + mi * 512);
#pragma unroll
    for (int ni = 0; ni < 4; ++ni) b[ni] = *(const short8*)(fb0 + ni * 512);
#pragma unroll
    for (int mi = 0; mi < 4; ++mi)
#pragma unroll
      for (int ni = 0; ni < 4; ++ni)
        acc[mi][ni] = __builtin_amdgcn_mfma_f32_16x16x32_bf16(a[mi], b[ni], acc[mi][ni], 0, 0, 0);
    __syncthreads();
  }
  int row0 = mt * 128 + wr + kg * 4;
  int col0 = nt * 128 + wc + r16;
  float* cp = part + (size_t)z * NBS * 256;
#pragma unroll
  for (int mi = 0; mi < 4; ++mi)
#pragma unroll
    for (int ni = 0; ni < 4; ++ni)
#pragma unroll
      for (int r = 0; r < 4; ++r)
        cp[(size_t)(row0 + mi * 16 + r) * 256 + col0 + ni * 16] = acc[mi][ni][r];
}

// ---------------- per-row glue: 4 rows/block, barrier-free, coalesced X stores ----------------
__global__ __launch_bounds__(256) void row_kernel(
    const float* __restrict__ obs, const float* __restrict__ QKV,
    const float* __restrict__ QKE, const float* __restrict__ QKA,
    const float* __restrict__ H1p, const float* __restrict__ Wb2,
    const float* __restrict__ bb2, const float* __restrict__ Wh2,
    const float* __restrict__ bh2, const float* __restrict__ bb1,
    const float* __restrict__ bh1, __hip_bfloat16* __restrict__ X,
    float* __restrict__ bterm) {
  __shared__ float qke_lds[4][64], qka_lds[4][64];
  __shared__ uint4 xstage[4][2][256];  // per-wave double-buffered swap area
  int wv = threadIdx.x >> 6;
  int lane = threadIdx.x & 63;
  int b = blockIdx.x * 4 + wv;
  qke_lds[wv][lane] = QKE[(size_t)b * 64 + lane];
  qka_lds[wv][lane] = QKA[(size_t)b * 64 + lane];
  const float* qkv = QKV + (size_t)b * 768;
  float q_h[4], km_h[4], vm_h[4];
#pragma unroll
  for (int h = 0; h < 4; ++h) {
    q_h[h] = qkv[h * 64 + lane];
    km_h[h] = qkv[256 + h * 64 + lane];
    vm_h[h] = qkv[512 + h * 64 + lane];
  }
  float l0[4];
#pragma unroll
  for (int h = 0; h < 4; ++h) l0[h] = wsum(q_h[h] * km_h[h]) * 0.125f;
  const float* ob = obs + (size_t)b * NIN;
  alignas(16) float en[16];
  alignas(16) float al[16];
  {
    const float4* ep = (const float4*)(ob + 4 + lane * 16);
    const float4* ap = (const float4*)(ob + 1028 + lane * 16);
#pragma unroll
    for (int i = 0; i < 4; ++i) {
      *(float4*)(en + 4 * i) = ep[i];
      *(float4*)(al + 4 * i) = ap[i];
    }
  }
  bool av = lane < 63;
  float lE[4], lA_[4];
#pragma unroll
  for (int h = 0; h < 4; ++h) {
    float sE = 0.f, sA = 0.f;
#pragma unroll
    for (int d = 0; d < 16; ++d) {
      sE += en[d] * qke_lds[wv][h * 16 + d];
      sA += al[d] * qka_lds[wv][h * 16 + d];
    }
    lE[h] = sE * 0.125f;
    lA_[h] = sA * 0.125f;
  }
  // b_term / w_head from 8 H1 partial slices
  float vb0 = 0.f, vw0 = 0.f, vw1 = 0.f;
  const size_t S1 = (size_t)NBS * 192;
#pragma unroll
  for (int z = 0; z < 8; ++z) {
    const float* p = H1p + (size_t)z * S1 + (size_t)b * 192;
    vb0 += p[lane];
    vw0 += p[64 + lane];
    vw1 += p[128 + lane];
  }
  float hb = fmaxf(vb0 + bb1[lane], 0.f);
  float bt = wsum(hb * Wb2[lane]) + bb2[0];
  float hw0 = fmaxf(vw0 + bh1[lane], 0.f);
  float hw1 = fmaxf(vw1 + bh1[64 + lane], 0.f);
  float whead[4];
#pragma unroll
  for (int h = 0; h < 4; ++h)
    whead[h] = fabsf(wsum(hw0 * Wh2[h * 128 + lane] + hw1 * Wh2[h * 128 + 64 + lane]) + bh2[h]);
  float wE[4], wA[4], w0[4];
#pragma unroll
  for (int h = 0; h < 4; ++h) {
    float mE = wmax(lE[h]);
    float mA = wmax(av ? lA_[h] : -3.0e38f);
    float mx = fmaxf(fmaxf(mE, mA), l0[h]);
    float pE = __expf(lE[h] - mx);
    float pA = av ? __expf(lA_[h] - mx) : 0.f;
    float p0 = __expf(l0[h] - mx);
    float den = wsum(pE + pA) + p0;
    float s = whead[h] / den;
    wE[h] = pE * s;
    wA[h] = pA * s;
    w0[h] = p0 * s;
  }
  // X row, layout k = h*2048 + (n-1)*16 + d; coalesced via LDS swap
  __hip_bfloat16* xr = X + (size_t)b * 8192;
#pragma unroll
  for (int h = 0; h < 4; ++h) {
    int buf = h & 1;
    uint ue[8], ua[8];
#pragma unroll
    for (int j = 0; j < 8; ++j) {
      __hip_bfloat16 lo = __float2bfloat16(wE[h] * en[2 * j]);
      __hip_bfloat16 hi = __float2bfloat16(wE[h] * en[2 * j + 1]);
      ue[j] = (uint)*(ushort*)&lo | ((uint)*(ushort*)&hi << 16);
      __hip_bfloat16 alo = __float2bfloat16(wA[h] * al[2 * j]);
      __hip_bfloat16 ahi = __float2bfloat16(wA[h] * al[2 * j + 1]);
      ua[j] = (uint)*(ushort*)&alo | ((uint)*(ushort*)&ahi << 16);
    }
    xstage[wv][buf][lane * 2] = make_uint4(ue[0], ue[1], ue[2], ue[3]);
    xstage[wv][buf][lane * 2 + 1] = make_uint4(ue[4], ue[5], ue[6], ue[7]);
    if (av) {
      xstage[wv][buf][(64 + lane) * 2] = make_uint4(ua[0], ua[1], ua[2], ua[3]);
      xstage[wv][buf][(64 + lane) * 2 + 1] = make_uint4(ua[4], ua[5], ua[6], ua[7]);
    }
#pragma unroll
    for (int s = 0; s < 4; ++s) {
      uint4 v = xstage[wv][buf][s * 64 + lane];
      if (!(s == 3 && lane >= 62))
        *(uint4*)(xr + h * 2048 + s * 512 + lane * 8) = v;
    }
  }
  float x0 = w0[0] * vm_h[0] + w0[1] * vm_h[1] + w0[2] * vm_h[2] + w0[3] * vm_h[3];
  xr[(lane >> 4) * 2048 + 2032 + (lane & 15)] = __float2bfloat16(x0);
  if (lane == 0) bterm[b] = bt;
}

// ---------------- final reduce + epilogue ----------------
__global__ void k7_out(const float* __restrict__ part, const float* __restrict__ bterm,
                       const float* __restrict__ rowsum, const float* __restrict__ bfv,
                       float* __restrict__ out) {
  int b = blockIdx.x, r = threadIdx.x;
  size_t i = (size_t)b * 256 + r;
  const size_t S = (size_t)NBS * 256;
  float v = 0.f;
#pragma unroll
  for (int z = 0; z < 8; ++z) v += part[i + z * S];
  out[i] = v + bterm[b] * rowsum[r] + bfv[r];
}

// ---------------- host ----------------
extern "C" void kernel_launch(void* const* d_in, const int* in_sizes, int n_in,
                              void* d_out, int out_size, void* d_ws, size_t ws_size,
                              hipStream_t stream) {
  const float* obs = (const float*)d_in[0];
  const float* Wq1 = (const float*)d_in[1];
  const float* bq1 = (const float*)d_in[2];
  const float* Wq2 = (const float*)d_in[3];
  const float* Wkm1 = (const float*)d_in[4];
  const float* bkm1 = (const float*)d_in[5];
  const float* Wkm2 = (const float*)d_in[6];
  const float* Wke = (const float*)d_in[7];
  const float* Wka = (const float*)d_in[8];
  const float* Wvm1 = (const float*)d_in[9];
  const float* bvm1 = (const float*)d_in[10];
  const float* Wvm2 = (const float*)d_in[11];
  const float* Wve = (const float*)d_in[12];
  const float* Wva = (const float*)d_in[13];
  const float* Wb1 = (const float*)d_in[14];
  const float* bb1 = (const float*)d_in[15];
  const float* Wb2 = (const float*)d_in[16];
  const float* bb2 = (const float*)d_in[17];
  const float* Wh1 = (const float*)d_in[18];
  const float* bh1 = (const float*)d_in[19];
  const float* Wh2 = (const float*)d_in[20];
  const float* bh2 = (const float*)d_in[21];
  const float* Wf = (const float*)d_in[22];
  const float* bfv = (const float*)d_in[23];
  float* out = (float*)d_out;

  char* ws = (char*)d_ws;
  size_t off = 0;
  auto alloc = [&](size_t bytes) -> void* {
    void* p = ws + off;
    off += (bytes + 255) & ~(size_t)255;
    return p;
  };
  __hip_bfloat16* mmat = (__hip_bfloat16*)alloc((size_t)NBS * 32 * 2);
  __hip_bfloat16* w1m = (__hip_bfloat16*)alloc((size_t)1536 * 32 * 2);
  float* b1cat = (float*)alloc(1536 * 4);
  __hip_bfloat16* w2cat = (__hip_bfloat16*)alloc((size_t)768 * 128 * 2);
  __hip_bfloat16* w1cat = (__hip_bfloat16*)alloc((size_t)192 * KPAD * 2);
  __hip_bfloat16* wket = (__hip_bfloat16*)alloc(4096 * 2);
  __hip_bfloat16* wkat = (__hip_bfloat16*)alloc(4096 * 2);
  float* rowsum = (float*)alloc(256 * 4);
  float* bterm = (float*)alloc(NBS * 4);
  float* QKE = (float*)alloc((size_t)NBS * 64 * 4);
  float* QKA = (float*)alloc((size_t)NBS * 64 * 4);
  float* Wft = (float*)alloc((size_t)8192 * 256 * 4);
  __hip_bfloat16* Yt = (__hip_bfloat16*)alloc((size_t)256 * 8192 * 2);
  __hip_bfloat16* X = (__hip_bfloat16*)alloc((size_t)NBS * 8192 * 2);
  // Aliased region: {QKV (12.6MB), H1p (25.2MB)} live until row_kernel;
  // part8 (33.6MB) lives after.
  char* R = (char*)alloc((size_t)39 * 1024 * 1024);
  float* QKV = (float*)R;
  float* H1p = (float*)(R + (size_t)NBS * 768 * 4);
  float* part8 = (float*)R;

  hipMemsetAsync(rowsum, 0, 256 * 4, stream);

  prep_small<<<1282, 256, 0, stream>>>(obs, Wb1, Wh1, Wq1, Wkm1, Wvm1, bq1, bkm1, bvm1,
                                       Wq2, Wkm2, Wvm2, Wke, Wka,
                                       mmat, w1cat, w1m, b1cat, w2cat, wket, wkat);
  p6a_twf<<<dim3(128, 4), 256, 0, stream>>>(Wf, Wft, rowsum);
  p6b_yt<<<128, 256, 0, stream>>>(Wft, Wve, Wva, Yt);

  // H1p[z] = obs(f32->bf16 fused) * w1cat^T, split-K=8 (2 blocks/CU)
  gemm_h1<<<dim3(64, 8), 256, 0, stream>>>(obs, w1cat, H1p);
  // QKV + QKE/QKA
  qkv_fused<<<dim3(64, 12), 256, 0, stream>>>(mmat, w1m, b1cat, w2cat, wket, wkat,
                                              QKV, QKE, QKA);
  // glue -> X (new layout), bterm
  row_kernel<<<NBS / 4, 256, 0, stream>>>(obs, QKV, QKE, QKA, H1p, Wb2, bb2, Wh2, bh2,
                                          bb1, bh1, X, bterm);
  // part8[z] = X[:, z*1024:+1024] * Yt[:, z*1024:+1024]^T
  gemm_final<<<512, 256, 0, stream>>>((const ushort*)X, (const ushort*)Yt, part8);
  k7_out<<<NBS, 256, 0, stream>>>(part8, bterm, rowsum, bfv, out);

  (void)in_sizes; (void)n_in; (void)out_size; (void)ws_size;
}

// Round 11
// 251.758 us; speedup vs baseline: 1.0493x; 1.0493x over previous
//
#include <hip/hip_runtime.h>
#include <hip/hip_bf16.h>

typedef __attribute__((ext_vector_type(8))) short short8;
typedef __attribute__((ext_vector_type(4))) float floatx4;

#define NIN 2056
#define KPAD 2080
#define NBS 4096

// ---------------- async global->LDS (16B) ----------------
__device__ __forceinline__ void gl_lds16(const ushort* g, ushort* l) {
#if defined(__has_builtin) && __has_builtin(__builtin_amdgcn_global_load_lds)
  __builtin_amdgcn_global_load_lds(
      (const __attribute__((address_space(1))) unsigned int*)g,
      (__attribute__((address_space(3))) unsigned int*)l, 16, 0, 0);
#else
  *(uint4*)l = *(const uint4*)g;
#endif
}

// ---------------- reductions ----------------
__device__ __forceinline__ float wsum(float v) {
#pragma unroll
  for (int o = 32; o; o >>= 1) v += __shfl_xor(v, o, 64);
  return v;
}
__device__ __forceinline__ float wmax(float v) {
#pragma unroll
  for (int o = 32; o; o >>= 1) v = fmaxf(v, __shfl_xor(v, o, 64));
  return v;
}

// ---------------- merged small preps ----------------
// [0,512): mmat; [512,704): w1cat; [704,896): w1m+b1cat; [896,1280): w2cat;
// 1280: wkeT; 1281: wkaT
__global__ void prep_small(const float* __restrict__ obs,
                           const float* __restrict__ Wb1, const float* __restrict__ Wh1,
                           const float* __restrict__ Wq1, const float* __restrict__ Wkm1,
                           const float* __restrict__ Wvm1, const float* __restrict__ bq1,
                           const float* __restrict__ bkm1, const float* __restrict__ bvm1,
                           const float* __restrict__ Wq2, const float* __restrict__ Wkm2,
                           const float* __restrict__ Wvm2,
                           const float* __restrict__ Wke, const float* __restrict__ Wka,
                           __hip_bfloat16* __restrict__ mmat,
                           __hip_bfloat16* __restrict__ w1cat,
                           __hip_bfloat16* __restrict__ w1m, float* __restrict__ b1cat,
                           __hip_bfloat16* __restrict__ w2cat,
                           __hip_bfloat16* __restrict__ wket,
                           __hip_bfloat16* __restrict__ wkat) {
  int bid = blockIdx.x, tid = threadIdx.x;
  if (bid < 512) {  // mmat [4096][32]
    int idx = bid * 256 + tid;
    int b = idx >> 5, j = idx & 31;
    float v = 0.f;
    if (j < 4) v = obs[(size_t)b * NIN + j];
    else if (j < 24) v = obs[(size_t)b * NIN + 2032 + j];
    mmat[idx] = __float2bfloat16(v);
  } else if (bid < 704) {  // w1cat [192][KPAD]
    int r = bid - 512;
    const float* src = (r < 64) ? (Wb1 + (size_t)r * NIN) : (Wh1 + (size_t)(r - 64) * NIN);
    for (int j = tid; j < KPAD; j += 256)
      w1cat[(size_t)r * KPAD + j] = __float2bfloat16(j < NIN ? src[j] : 0.f);
  } else if (bid < 896) {  // w1m [1536][32], b1cat
    int idx = (bid - 704) * 256 + tid;
    int row = idx >> 5, j = idx & 31;
    int net = row >> 9, hg = row & 511;
    const float* W1 = net == 0 ? Wq1 : (net == 1 ? Wkm1 : Wvm1);
    float v = (j < 24) ? W1[(size_t)hg * 24 + j] : 0.f;
    w1m[idx] = __float2bfloat16(v);
    if (j == 0) {
      const float* b1 = net == 0 ? bq1 : (net == 1 ? bkm1 : bvm1);
      b1cat[row] = b1[hg];
    }
  } else if (bid < 1280) {  // w2cat [768][128]
    int idx = (bid - 896) * 256 + tid;
    int row = idx >> 7, g = idx & 127;
    int net = row >> 8, he = row & 255;
    const float* W2 = net == 0 ? Wq2 : (net == 1 ? Wkm2 : Wvm2);
    w2cat[idx] = __float2bfloat16(W2[(size_t)he * 128 + g]);
  } else {  // wkeT/wkaT [h*16+d][64 e] bf16
    const float* W = (bid == 1280) ? Wke : Wka;
    __hip_bfloat16* dst = (bid == 1280) ? wket : wkat;
    for (int j = tid; j < 4096; j += 256) {
      int e = j & 63, hd = j >> 6;
      int h = hd >> 4, d = hd & 15;
      dst[j] = __float2bfloat16(W[h * 1024 + e * 16 + d]);
    }
  }
}

// transpose Wf [256][8192] -> Wft [8192][256]; fold in rowsum
__global__ void p6a_twf(const float* __restrict__ Wf, float* __restrict__ Wft,
                        float* __restrict__ rowsum) {
  __shared__ float t[64][65];
  int kt = blockIdx.x, rt = blockIdx.y;
  int tid = threadIdx.x;
  int kl = tid & 63, r0 = tid >> 6;
#pragma unroll
  for (int ii = 0; ii < 16; ++ii) {
    int rl = ii * 4 + r0;
    t[rl][kl] = Wf[(size_t)(rt * 64 + rl) * 8192 + kt * 64 + kl];
  }
  __syncthreads();
#pragma unroll
  for (int ii = 0; ii < 16; ++ii) {
    int kl2 = ii * 4 + r0;
    Wft[(size_t)(kt * 64 + kl2) * 256 + rt * 64 + kl] = t[kl][kl2];
  }
  if (tid < 64) {
    float s = 0.f;
    for (int kk = 0; kk < 64; ++kk) s += t[tid][kk];
    atomicAdd(&rowsum[rt * 64 + tid], s);
  }
}

// Yt layout: k = h*2048 + (n-1)*16 + d for entities; e-basis at h'*2048+2032+(e&15)
__global__ void p6b_yt(const float* __restrict__ Wft, const float* __restrict__ Wve,
                       const float* __restrict__ Wva, __hip_bfloat16* __restrict__ Yt) {
  int n = blockIdx.x;   // 0..127
  int r = threadIdx.x;  // 0..255
  if (n == 0) {
    alignas(16) __hip_bfloat16 tmp[8];
    for (int e0 = 0; e0 < 64; e0 += 8) {
#pragma unroll
      for (int j = 0; j < 8; ++j)
        tmp[j] = __float2bfloat16(Wft[(size_t)((e0 + j) * 128) * 256 + r]);
      *(uint4*)(Yt + (size_t)r * 8192 + (e0 >> 4) * 2048 + 2032 + (e0 & 15)) =
          *(const uint4*)tmp;
    }
    return;
  }
  const float* Wv = (n <= 64) ? Wve : Wva;
  float accv[64];
#pragma unroll
  for (int j = 0; j < 64; ++j) accv[j] = 0.f;
  for (int e = 0; e < 64; ++e) {
    float v = Wft[(size_t)(e * 128 + n) * 256 + r];
#pragma unroll
    for (int hd = 0; hd < 64; ++hd)
      accv[hd] += Wv[(hd >> 4) * 1024 + e * 16 + (hd & 15)] * v;
  }
#pragma unroll
  for (int c = 0; c < 8; ++c) {
    alignas(16) __hip_bfloat16 tmp[8];
#pragma unroll
    for (int j = 0; j < 8; ++j) tmp[j] = __float2bfloat16(accv[c * 8 + j]);
    // hd = c*8+j -> h = c>>1, d = (c&1)*8+j
    *(uint4*)(Yt + (size_t)r * 8192 + (c >> 1) * 2048 + (size_t)(n - 1) * 16 + (c & 1) * 8) =
        *(const uint4*)tmp;
  }
}

// ---------------- fused HID+QKV (+ qke/qka MFMA for z<4) ----------------
__global__ __launch_bounds__(256) void qkv_fused(
    const __hip_bfloat16* __restrict__ mmat_, const __hip_bfloat16* __restrict__ w1m_,
    const float* __restrict__ b1cat, const __hip_bfloat16* __restrict__ w2cat_,
    const __hip_bfloat16* __restrict__ wket_, const __hip_bfloat16* __restrict__ wkat_,
    float* __restrict__ QKV, float* __restrict__ QKE, float* __restrict__ QKA) {
  __shared__ alignas(16) ushort lH[64 * 136];
  __shared__ alignas(16) ushort lq[64 * 72];
  const ushort* mmat = (const ushort*)mmat_;
  const ushort* w1m = (const ushort*)w1m_;
  const ushort* w2cat = (const ushort*)w2cat_;
  const ushort* wket = (const ushort*)wket_;
  const ushort* wkat = (const ushort*)wkat_;
  int mt = blockIdx.x, z = blockIdx.y;
  int t = threadIdx.x;
  int w = t >> 6, l = t & 63, r16 = l & 15, kg = l >> 4;
  floatx4 zero4 = {0.f, 0.f, 0.f, 0.f};
  // GEMM1: hidden = relu(mmat * w1m[z]^T + b1)
  short8 a1 = *(const short8*)(mmat + (size_t)(mt * 64 + w * 16 + r16) * 32 + kg * 8);
  floatx4 acc1[8];
#pragma unroll
  for (int c = 0; c < 8; ++c) {
    short8 b1 = *(const short8*)(w1m + (size_t)(z * 128 + c * 16 + r16) * 32 + kg * 8);
    acc1[c] = __builtin_amdgcn_mfma_f32_16x16x32_bf16(a1, b1, zero4, 0, 0, 0);
  }
#pragma unroll
  for (int c = 0; c < 8; ++c) {
    int col = c * 16 + r16;
    float bias = b1cat[z * 128 + col];
#pragma unroll
    for (int r = 0; r < 4; ++r) {
      float v = acc1[c][r] + bias;
      v = v > 0.f ? v : 0.f;
      __hip_bfloat16 bv = __float2bfloat16(v);
      lH[(w * 16 + kg * 4 + r) * 136 + col] = *(ushort*)&bv;
    }
  }
  __syncthreads();
  // GEMM2: out = hidden * w2cat[z]^T
  floatx4 acc2[4] = {zero4, zero4, zero4, zero4};
#pragma unroll
  for (int ks = 0; ks < 4; ++ks) {
    short8 a = *(const short8*)(lH + (w * 16 + r16) * 136 + ks * 32 + kg * 8);
#pragma unroll
    for (int c = 0; c < 4; ++c) {
      short8 b = *(const short8*)(w2cat + (size_t)(z * 64 + c * 16 + r16) * 128 + ks * 32 + kg * 8);
      acc2[c] = __builtin_amdgcn_mfma_f32_16x16x32_bf16(a, b, acc2[c], 0, 0, 0);
    }
  }
  float* Q = QKV + (size_t)(mt * 64) * 768 + z * 64;
#pragma unroll
  for (int c = 0; c < 4; ++c)
#pragma unroll
    for (int r = 0; r < 4; ++r)
      Q[(size_t)(w * 16 + kg * 4 + r) * 768 + c * 16 + r16] = acc2[c][r];
  // qke/qka = q @ WkeT/WkaT via MFMA (q heads only: z<4, h=z)
  if (z < 4) {
#pragma unroll
    for (int c = 0; c < 4; ++c)
#pragma unroll
      for (int r = 0; r < 4; ++r) {
        __hip_bfloat16 bv = __float2bfloat16(acc2[c][r]);
        lq[(w * 16 + kg * 4 + r) * 72 + c * 16 + r16] = *(ushort*)&bv;
      }
    short8 a0 = *(const short8*)(lq + (w * 16 + r16) * 72 + kg * 8);
    short8 a1q = *(const short8*)(lq + (w * 16 + r16) * 72 + 32 + kg * 8);
    const ushort* bke = wket + (size_t)(z * 16 + r16) * 64 + kg * 8;
    const ushort* bka = wkat + (size_t)(z * 16 + r16) * 64 + kg * 8;
    short8 bk0 = *(const short8*)bke;
    short8 bk1 = *(const short8*)(bke + 32);
    short8 ba0 = *(const short8*)bka;
    short8 ba1 = *(const short8*)(bka + 32);
    floatx4 ke = __builtin_amdgcn_mfma_f32_16x16x32_bf16(a0, bk0, zero4, 0, 0, 0);
    ke = __builtin_amdgcn_mfma_f32_16x16x32_bf16(a1q, bk1, ke, 0, 0, 0);
    floatx4 ka = __builtin_amdgcn_mfma_f32_16x16x32_bf16(a0, ba0, zero4, 0, 0, 0);
    ka = __builtin_amdgcn_mfma_f32_16x16x32_bf16(a1q, ba1, ka, 0, 0, 0);
#pragma unroll
    for (int r = 0; r < 4; ++r) {
      size_t row = (size_t)(mt * 64 + w * 16 + kg * 4 + r);
      QKE[row * 64 + z * 16 + r16] = ke[r];
      QKA[row * 64 + z * 16 + r16] = ka[r];
    }
  }
}

// ---------------- H1 GEMM: 64 rows x 64 cols per block, split-K=8, prefetch ----------------
// nt in [0,3): output cols [nt*64, nt*64+64); z covers K-iters [z*8, z*8+8);
// z==7 also takes the padded tail iter 64.
__global__ __launch_bounds__(256) void gemm_h1(
    const float* __restrict__ obs, const __hip_bfloat16* __restrict__ w1cat_,
    float* __restrict__ H1p) {
  __shared__ alignas(16) ushort lA[64 * 40];
  __shared__ alignas(16) ushort lB[64 * 40];
  const ushort* w1cat = (const ushort*)w1cat_;
  int mt = blockIdx.x, nt = blockIdx.y, z = blockIdx.z;
  int t = threadIdx.x;
  int w = t >> 6, l = t & 63, r16 = l & 15, kg = l >> 4;
  int srow = t >> 2, sc = (t & 3) * 8;
  int k0 = z * 256;
  const float* ga = obs + (size_t)(mt * 64 + srow) * NIN + k0 + sc;
  const ushort* gb = w1cat + (size_t)(nt * 64 + srow) * KPAD + k0 + sc;
  ushort* sa = lA + srow * 40 + sc;
  ushort* sb = lB + srow * 40 + sc;
  const ushort* fa = lA + (w * 16 + r16) * 40 + kg * 8;
  const ushort* fb0 = lB + r16 * 40 + kg * 8;
  floatx4 zero4 = {0.f, 0.f, 0.f, 0.f};
  floatx4 acc[4] = {zero4, zero4, zero4, zero4};
  int nK = (z == 7) ? 9 : 8;
  bool aok = (t & 3) == 0;  // tail-iter A validity
  // prefetch iter 0
  float4 f0c, f1c;
  uint4 vbc;
  {
    f0c = *(const float4*)(ga);
    f1c = *(const float4*)(ga + 4);
    vbc = *(const uint4*)(gb);
  }
  for (int ks = 0; ks < nK; ++ks) {
    __syncthreads();  // drains prefetched loads (they flew during prior MFMA)
    alignas(16) __hip_bfloat16 tmp[8];
    tmp[0] = __float2bfloat16(f0c.x); tmp[1] = __float2bfloat16(f0c.y);
    tmp[2] = __float2bfloat16(f0c.z); tmp[3] = __float2bfloat16(f0c.w);
    tmp[4] = __float2bfloat16(f1c.x); tmp[5] = __float2bfloat16(f1c.y);
    tmp[6] = __float2bfloat16(f1c.z); tmp[7] = __float2bfloat16(f1c.w);
    *(uint4*)sa = *(const uint4*)tmp;
    *(uint4*)sb = vbc;
    __syncthreads();  // LDS tile visible
    // prefetch next iter (vmcnt waited at next top-of-loop barrier)
    if (ks + 1 < nK) {
      bool tail = (z == 7 && ks + 1 == 8);
      if (!tail || aok) {
        f0c = *(const float4*)(ga + (ks + 1) * 32);
        f1c = *(const float4*)(ga + (ks + 1) * 32 + 4);
      } else {
        f0c = make_float4(0.f, 0.f, 0.f, 0.f);
        f1c = make_float4(0.f, 0.f, 0.f, 0.f);
      }
      vbc = *(const uint4*)(gb + (ks + 1) * 32);
    }
    short8 a = *(const short8*)fa;
#pragma unroll
    for (int c = 0; c < 4; ++c) {
      short8 bb = *(const short8*)(fb0 + c * 16 * 40);
      acc[c] = __builtin_amdgcn_mfma_f32_16x16x32_bf16(a, bb, acc[c], 0, 0, 0);
    }
  }
  float* C = H1p + (size_t)z * NBS * 192;
  int row0 = mt * 64 + w * 16 + kg * 4;
  int col0 = nt * 64 + r16;
#pragma unroll
  for (int c = 0; c < 4; ++c)
#pragma unroll
    for (int r = 0; r < 4; ++r)
      C[(size_t)(row0 + r) * 192 + col0 + c * 16] = acc[c][r];
}

// ---------------- final GEMM: 128x128 tile, BK=32, split-K=8 ----------------
__global__ __launch_bounds__(256) void gemm_final(
    const ushort* __restrict__ Xg, const ushort* __restrict__ Yt,
    float* __restrict__ part) {
  __shared__ alignas(16) ushort lA[128 * 32];
  __shared__ alignas(16) ushort lB[128 * 32];
  int bid = blockIdx.x;
  int z = bid & 7, nt = (bid >> 3) & 1, mt = bid >> 4;
  int t = threadIdx.x;
  int w = t >> 6, l = t & 63, r16 = l & 15, kg = l >> 4;
  int wr = (w >> 1) * 64, wc = (w & 1) * 64;
  const ushort* ga0 = Xg + (size_t)(mt * 128 + (t >> 2)) * 8192 + z * 1024 + (t & 3) * 8;
  const ushort* ga1 = ga0 + (size_t)64 * 8192;
  const ushort* gb0 = Yt + (size_t)(nt * 128 + (t >> 2)) * 8192 + z * 1024 + (t & 3) * 8;
  const ushort* gb1 = gb0 + (size_t)64 * 8192;
  ushort* la0 = lA + t * 8;
  ushort* la1 = lA + 2048 + t * 8;
  ushort* lb0 = lB + t * 8;
  ushort* lb1 = lB + 2048 + t * 8;
  const ushort* fa0 = lA + (wr + r16) * 32 + kg * 8;
  const ushort* fb0 = lB + (wc + r16) * 32 + kg * 8;
  floatx4 zero4 = {0.f, 0.f, 0.f, 0.f};
  floatx4 acc[4][4];
#pragma unroll
  for (int i = 0; i < 4; ++i)
#pragma unroll
    for (int j = 0; j < 4; ++j) acc[i][j] = zero4;
  for (int ks = 0; ks < 32; ++ks) {
    gl_lds16(ga0, la0);
    gl_lds16(ga1, la1);
    gl_lds16(gb0, lb0);
    gl_lds16(gb1, lb1);
    ga0 += 32; ga1 += 32; gb0 += 32; gb1 += 32;
    __syncthreads();
    short8 a[4], b[4];
#pragma unroll
    for (int mi = 0; mi < 4; ++mi) a[mi] = *(const short8*)(fa0 + mi * 512);
#pragma unroll
    for (int ni = 0; ni < 4; ++ni) b[ni] = *(const short8*)(fb0 + ni * 512);
#pragma unroll
    for (int mi = 0; mi < 4; ++mi)
#pragma unroll
      for (int ni = 0; ni < 4; ++ni)
        acc[mi][ni] = __builtin_amdgcn_mfma_f32_16x16x32_bf16(a[mi], b[ni], acc[mi][ni], 0, 0, 0);
    __syncthreads();
  }
  int row0 = mt * 128 + wr + kg * 4;
  int col0 = nt * 128 + wc + r16;
  float* cp = part + (size_t)z * NBS * 256;
#pragma unroll
  for (int mi = 0; mi < 4; ++mi)
#pragma unroll
    for (int ni = 0; ni < 4; ++ni)
#pragma unroll
      for (int r = 0; r < 4; ++r)
        cp[(size_t)(row0 + mi * 16 + r) * 256 + col0 + ni * 16] = acc[mi][ni][r];
}

// ---------------- per-row glue: 4 rows/block, barrier-free, coalesced X stores ----------------
__global__ __launch_bounds__(256) void row_kernel(
    const float* __restrict__ obs, const float* __restrict__ QKV,
    const float* __restrict__ QKE, const float* __restrict__ QKA,
    const float* __restrict__ H1p, const float* __restrict__ Wb2,
    const float* __restrict__ bb2, const float* __restrict__ Wh2,
    const float* __restrict__ bh2, const float* __restrict__ bb1,
    const float* __restrict__ bh1, __hip_bfloat16* __restrict__ X,
    float* __restrict__ bterm) {
  __shared__ float qke_lds[4][64], qka_lds[4][64];
  __shared__ uint4 xstage[4][2][256];  // per-wave double-buffered swap area
  int wv = threadIdx.x >> 6;
  int lane = threadIdx.x & 63;
  int b = blockIdx.x * 4 + wv;
  qke_lds[wv][lane] = QKE[(size_t)b * 64 + lane];
  qka_lds[wv][lane] = QKA[(size_t)b * 64 + lane];
  const float* qkv = QKV + (size_t)b * 768;
  float q_h[4], km_h[4], vm_h[4];
#pragma unroll
  for (int h = 0; h < 4; ++h) {
    q_h[h] = qkv[h * 64 + lane];
    km_h[h] = qkv[256 + h * 64 + lane];
    vm_h[h] = qkv[512 + h * 64 + lane];
  }
  float l0[4];
#pragma unroll
  for (int h = 0; h < 4; ++h) l0[h] = wsum(q_h[h] * km_h[h]) * 0.125f;
  const float* ob = obs + (size_t)b * NIN;
  alignas(16) float en[16];
  alignas(16) float al[16];
  {
    const float4* ep = (const float4*)(ob + 4 + lane * 16);
    const float4* ap = (const float4*)(ob + 1028 + lane * 16);
#pragma unroll
    for (int i = 0; i < 4; ++i) {
      *(float4*)(en + 4 * i) = ep[i];
      *(float4*)(al + 4 * i) = ap[i];
    }
  }
  bool av = lane < 63;
  float lE[4], lA_[4];
#pragma unroll
  for (int h = 0; h < 4; ++h) {
    float sE = 0.f, sA = 0.f;
#pragma unroll
    for (int d = 0; d < 16; ++d) {
      sE += en[d] * qke_lds[wv][h * 16 + d];
      sA += al[d] * qka_lds[wv][h * 16 + d];
    }
    lE[h] = sE * 0.125f;
    lA_[h] = sA * 0.125f;
  }
  // b_term / w_head from 8 H1 partial slices
  float vb0 = 0.f, vw0 = 0.f, vw1 = 0.f;
  const size_t S1 = (size_t)NBS * 192;
#pragma unroll
  for (int z = 0; z < 8; ++z) {
    const float* p = H1p + (size_t)z * S1 + (size_t)b * 192;
    vb0 += p[lane];
    vw0 += p[64 + lane];
    vw1 += p[128 + lane];
  }
  float hb = fmaxf(vb0 + bb1[lane], 0.f);
  float bt = wsum(hb * Wb2[lane]) + bb2[0];
  float hw0 = fmaxf(vw0 + bh1[lane], 0.f);
  float hw1 = fmaxf(vw1 + bh1[64 + lane], 0.f);
  float whead[4];
#pragma unroll
  for (int h = 0; h < 4; ++h)
    whead[h] = fabsf(wsum(hw0 * Wh2[h * 128 + lane] + hw1 * Wh2[h * 128 + 64 + lane]) + bh2[h]);
  float wE[4], wA[4], w0[4];
#pragma unroll
  for (int h = 0; h < 4; ++h) {
    float mE = wmax(lE[h]);
    float mA = wmax(av ? lA_[h] : -3.0e38f);
    float mx = fmaxf(fmaxf(mE, mA), l0[h]);
    float pE = __expf(lE[h] - mx);
    float pA = av ? __expf(lA_[h] - mx) : 0.f;
    float p0 = __expf(l0[h] - mx);
    float den = wsum(pE + pA) + p0;
    float s = whead[h] / den;
    wE[h] = pE * s;
    wA[h] = pA * s;
    w0[h] = p0 * s;
  }
  // X row, layout k = h*2048 + (n-1)*16 + d; coalesced via LDS swap
  __hip_bfloat16* xr = X + (size_t)b * 8192;
#pragma unroll
  for (int h = 0; h < 4; ++h) {
    int buf = h & 1;
    uint ue[8], ua[8];
#pragma unroll
    for (int j = 0; j < 8; ++j) {
      __hip_bfloat16 lo = __float2bfloat16(wE[h] * en[2 * j]);
      __hip_bfloat16 hi = __float2bfloat16(wE[h] * en[2 * j + 1]);
      ue[j] = (uint)*(ushort*)&lo | ((uint)*(ushort*)&hi << 16);
      __hip_bfloat16 alo = __float2bfloat16(wA[h] * al[2 * j]);
      __hip_bfloat16 ahi = __float2bfloat16(wA[h] * al[2 * j + 1]);
      ua[j] = (uint)*(ushort*)&alo | ((uint)*(ushort*)&ahi << 16);
    }
    xstage[wv][buf][lane * 2] = make_uint4(ue[0], ue[1], ue[2], ue[3]);
    xstage[wv][buf][lane * 2 + 1] = make_uint4(ue[4], ue[5], ue[6], ue[7]);
    if (av) {
      xstage[wv][buf][(64 + lane) * 2] = make_uint4(ua[0], ua[1], ua[2], ua[3]);
      xstage[wv][buf][(64 + lane) * 2 + 1] = make_uint4(ua[4], ua[5], ua[6], ua[7]);
    }
#pragma unroll
    for (int s = 0; s < 4; ++s) {
      uint4 v = xstage[wv][buf][s * 64 + lane];
      if (!(s == 3 && lane >= 62))
        *(uint4*)(xr + h * 2048 + s * 512 + lane * 8) = v;
    }
  }
  float x0 = w0[0] * vm_h[0] + w0[1] * vm_h[1] + w0[2] * vm_h[2] + w0[3] * vm_h[3];
  xr[(lane >> 4) * 2048 + 2032 + (lane & 15)] = __float2bfloat16(x0);
  if (lane == 0) bterm[b] = bt;
}

// ---------------- final reduce + epilogue ----------------
__global__ void k7_out(const float* __restrict__ part, const float* __restrict__ bterm,
                       const float* __restrict__ rowsum, const float* __restrict__ bfv,
                       float* __restrict__ out) {
  int b = blockIdx.x, r = threadIdx.x;
  size_t i = (size_t)b * 256 + r;
  const size_t S = (size_t)NBS * 256;
  float v = 0.f;
#pragma unroll
  for (int z = 0; z < 8; ++z) v += part[i + z * S];
  out[i] = v + bterm[b] * rowsum[r] + bfv[r];
}

// ---------------- host ----------------
extern "C" void kernel_launch(void* const* d_in, const int* in_sizes, int n_in,
                              void* d_out, int out_size, void* d_ws, size_t ws_size,
                              hipStream_t stream) {
  const float* obs = (const float*)d_in[0];
  const float* Wq1 = (const float*)d_in[1];
  const float* bq1 = (const float*)d_in[2];
  const float* Wq2 = (const float*)d_in[3];
  const float* Wkm1 = (const float*)d_in[4];
  const float* bkm1 = (const float*)d_in[5];
  const float* Wkm2 = (const float*)d_in[6];
  const float* Wke = (const float*)d_in[7];
  const float* Wka = (const float*)d_in[8];
  const float* Wvm1 = (const float*)d_in[9];
  const float* bvm1 = (const float*)d_in[10];
  const float* Wvm2 = (const float*)d_in[11];
  const float* Wve = (const float*)d_in[12];
  const float* Wva = (const float*)d_in[13];
  const float* Wb1 = (const float*)d_in[14];
  const float* bb1 = (const float*)d_in[15];
  const float* Wb2 = (const float*)d_in[16];
  const float* bb2 = (const float*)d_in[17];
  const float* Wh1 = (const float*)d_in[18];
  const float* bh1 = (const float*)d_in[19];
  const float* Wh2 = (const float*)d_in[20];
  const float* bh2 = (const float*)d_in[21];
  const float* Wf = (const float*)d_in[22];
  const float* bfv = (const float*)d_in[23];
  float* out = (float*)d_out;

  char* ws = (char*)d_ws;
  size_t off = 0;
  auto alloc = [&](size_t bytes) -> void* {
    void* p = ws + off;
    off += (bytes + 255) & ~(size_t)255;
    return p;
  };
  __hip_bfloat16* mmat = (__hip_bfloat16*)alloc((size_t)NBS * 32 * 2);
  __hip_bfloat16* w1m = (__hip_bfloat16*)alloc((size_t)1536 * 32 * 2);
  float* b1cat = (float*)alloc(1536 * 4);
  __hip_bfloat16* w2cat = (__hip_bfloat16*)alloc((size_t)768 * 128 * 2);
  __hip_bfloat16* w1cat = (__hip_bfloat16*)alloc((size_t)192 * KPAD * 2);
  __hip_bfloat16* wket = (__hip_bfloat16*)alloc(4096 * 2);
  __hip_bfloat16* wkat = (__hip_bfloat16*)alloc(4096 * 2);
  float* rowsum = (float*)alloc(256 * 4);
  float* bterm = (float*)alloc(NBS * 4);
  float* QKE = (float*)alloc((size_t)NBS * 64 * 4);
  float* QKA = (float*)alloc((size_t)NBS * 64 * 4);
  float* Wft = (float*)alloc((size_t)8192 * 256 * 4);
  __hip_bfloat16* Yt = (__hip_bfloat16*)alloc((size_t)256 * 8192 * 2);
  __hip_bfloat16* X = (__hip_bfloat16*)alloc((size_t)NBS * 8192 * 2);
  // Aliased region: {QKV (12.6MB), H1p (25.2MB)} live until row_kernel;
  // part8 (33.6MB) lives after.
  char* R = (char*)alloc((size_t)39 * 1024 * 1024);
  float* QKV = (float*)R;
  float* H1p = (float*)(R + (size_t)NBS * 768 * 4);
  float* part8 = (float*)R;

  hipMemsetAsync(rowsum, 0, 256 * 4, stream);

  prep_small<<<1282, 256, 0, stream>>>(obs, Wb1, Wh1, Wq1, Wkm1, Wvm1, bq1, bkm1, bvm1,
                                       Wq2, Wkm2, Wvm2, Wke, Wka,
                                       mmat, w1cat, w1m, b1cat, w2cat, wket, wkat);
  p6a_twf<<<dim3(128, 4), 256, 0, stream>>>(Wf, Wft, rowsum);
  p6b_yt<<<128, 256, 0, stream>>>(Wft, Wve, Wva, Yt);

  // H1p[z] = obs(f32->bf16 fused) * w1cat^T, N=64/block, split-K=8 (6 blocks/CU)
  gemm_h1<<<dim3(64, 3, 8), 256, 0, stream>>>(obs, w1cat, H1p);
  // QKV + QKE/QKA
  qkv_fused<<<dim3(64, 12), 256, 0, stream>>>(mmat, w1m, b1cat, w2cat, wket, wkat,
                                              QKV, QKE, QKA);
  // glue -> X (new layout), bterm
  row_kernel<<<NBS / 4, 256, 0, stream>>>(obs, QKV, QKE, QKA, H1p, Wb2, bb2, Wh2, bh2,
                                          bb1, bh1, X, bterm);
  // part8[z] = X[:, z*1024:+1024] * Yt[:, z*1024:+1024]^T
  gemm_final<<<512, 256, 0, stream>>>((const ushort*)X, (const ushort*)Yt, part8);
  k7_out<<<NBS, 256, 0, stream>>>(part8, bterm, rowsum, bfv, out);

  (void)in_sizes; (void)n_in; (void)out_size; (void)ws_size;
}